// Round 1
// baseline (262.465 us; speedup 1.0000x reference)
//
#include <hip/hip_runtime.h>
#include <math.h>

#define NB 2
#define NP 1200
#define NF 1000
#define IH 128
#define IW 128
#define TH 512
#define TW 512

// 80-byte per-face record, 16B-aligned so we can stage with float4 loads.
struct __align__(16) Face {
    float c[9];                       // edge-function coefficients (3 rows x 3)
    float z[3];                       // camera-space z per vertex
    float u0x,u0y,u1x,u1y,u2x,u2y;    // per-face uv
    float front;                      // normal.z > 0 ? 1 : 0
    float pad;
};

__global__ void prep_kernel(const float* __restrict__ points,
                            const int*  __restrict__ faces,
                            const float* __restrict__ rot,
                            const float* __restrict__ cpos,
                            const float* __restrict__ proj,
                            const float* __restrict__ uvp,
                            const int*  __restrict__ ft,
                            float* __restrict__ normal_out,
                            Face* __restrict__ fdata)
{
#pragma clang fp contract(off)
    int t = blockIdx.x * blockDim.x + threadIdx.x;
    if (t >= NB * NF) return;
    int b = t / NF;
    int f = t - b * NF;
    const float* R = rot + b * 9;
    float ccx = cpos[b*3+0], ccy = cpos[b*3+1], ccz = cpos[b*3+2];
    float pr0 = proj[0], pr1 = proj[1], pr2 = proj[2];

    float q[3][3];
    float sx[3], sy[3];
    for (int k = 0; k < 3; ++k) {
        int vi = faces[f*3 + k];
        const float* P = points + (b*NP + vi) * 3;
        float vx = P[0] - ccx, vy = P[1] - ccy, vz = P[2] - ccz;
        // pts = (p - c) @ R^T  ->  pts_j = ((v0*R[j,0] + v1*R[j,1]) + v2*R[j,2])
        float q0 = (vx*R[0] + vy*R[1]) + vz*R[2];
        float q1 = (vx*R[3] + vy*R[4]) + vz*R[5];
        float q2 = (vx*R[6] + vy*R[7]) + vz*R[8];
        q[k][0] = q0; q[k][1] = q1; q[k][2] = q2;
        sx[k] = (q0*pr0) / (q2*pr2);   // IEEE divide, same order as reference
        sy[k] = (q1*pr1) / (q2*pr2);
    }

    Face fd;
    float x0 = sx[0], y0 = sy[0];
    float x1 = sx[1], y1 = sy[1];
    float x2 = sx[2], y2 = sy[2];
    fd.c[0] = y1 - y2;  fd.c[1] = x2 - x1;  fd.c[2] = x1*y2 - x2*y1;
    fd.c[3] = y2 - y0;  fd.c[4] = x0 - x2;  fd.c[5] = x2*y0 - x0*y2;
    fd.c[6] = y0 - y1;  fd.c[7] = x1 - x0;  fd.c[8] = x0*y1 - x1*y0;
    fd.z[0] = q[0][2]; fd.z[1] = q[1][2]; fd.z[2] = q[2][2];

    float e1x = q[1][0]-q[0][0], e1y = q[1][1]-q[0][1], e1z = q[1][2]-q[0][2];
    float e2x = q[2][0]-q[0][0], e2y = q[2][1]-q[0][1], e2z = q[2][2]-q[0][2];
    float nx = e1y*e2z - e1z*e2y;
    float ny = e1z*e2x - e1x*e2z;
    float nz = e1x*e2y - e1y*e2x;
    fd.front = (nz > 0.0f) ? 1.0f : 0.0f;
    float nlen = sqrtf(((nx*nx + ny*ny) + nz*nz) + 1e-8f);
    float nd = nlen + 1e-15f;
    normal_out[t*3+0] = nx / nd;
    normal_out[t*3+1] = ny / nd;
    normal_out[t*3+2] = nz / nd;

    int j0 = ft[f*3+0], j1 = ft[f*3+1], j2 = ft[f*3+2];
    fd.u0x = uvp[(b*NP+j0)*2+0]; fd.u0y = uvp[(b*NP+j0)*2+1];
    fd.u1x = uvp[(b*NP+j1)*2+0]; fd.u1y = uvp[(b*NP+j1)*2+1];
    fd.u2x = uvp[(b*NP+j2)*2+0]; fd.u2y = uvp[(b*NP+j2)*2+1];
    fd.pad = 0.0f;
    fdata[t] = fd;
}

#define CHUNK 256
#define BLK 128

__global__ void raster_kernel(const Face* __restrict__ fdata,
                              const float* __restrict__ tex,
                              float* __restrict__ imrender,
                              float* __restrict__ improb)
{
#pragma clang fp contract(off)
    __shared__ float lds[CHUNK * 20];

    int pix = blockIdx.x * BLK + threadIdx.x;   // blocks never straddle batches
    int b = pix / (IH * IW);
    int p = pix - b * (IH * IW);
    int py_i = p / IW;
    int px_i = p - py_i * IW;
    // xs = (x+0.5)/W*2-1 ; ys = 1 - (y+0.5)/H*2   (exact reference order)
    float px = (px_i + 0.5f) / (float)IW * 2.0f - 1.0f;
    float py = 1.0f - (py_i + 0.5f) / (float)IH * 2.0f;

    const Face* fb = fdata + b * NF;

    float zmin = INFINITY;
    int idxsel = 0;
    float b0s = 0.0f, b1s = 0.0f, b2s = 0.0f;
    bool covered = false;
    float maxd = -INFINITY;
    bool hasfront = false;

    for (int base = 0; base < NF; base += CHUNK) {
        int cnt = min(CHUNK, NF - base);
        __syncthreads();
        {   // cooperative stage: cnt faces * 5 float4 each
            const float4* src = (const float4*)(fb + base);
            float4* dst = (float4*)lds;
            for (int i = threadIdx.x; i < cnt * 5; i += BLK) dst[i] = src[i];
        }
        __syncthreads();

        for (int j = 0; j < cnt; ++j) {
            const float* F_ = lds + j * 20;
            float w0 = (F_[0]*px + F_[1]*py) + F_[2];
            float w1 = (F_[3]*px + F_[4]*py) + F_[5];
            float w2 = (F_[6]*px + F_[7]*py) + F_[8];
            float den = (w0 + w1) + w2;
            den = den + ((den >= 0.0f) ? 1e-8f : -1e-8f);
            bool sp = den > 0.0f;
            // dmin = min_i(w_i/den): division by common den is monotone, so one divide
            float mn = fminf(fminf(w0, w1), w2);
            float mx = fmaxf(fmaxf(w0, w1), w2);
            float wsel = sp ? mn : mx;
            float dmin = wsel / den;
            float fr = F_[18];
            if (fr > 0.0f) { maxd = fmaxf(maxd, dmin); hasfront = true; }
            // inside test without division (sign-exact vs bary_i >= 0)
            bool inside = sp ? (w0 >= 0.0f && w1 >= 0.0f && w2 >= 0.0f)
                             : (w0 <= 0.0f && w1 <= 0.0f && w2 <= 0.0f);
            if (inside && fr > 0.0f) {
                float b0 = w0 / den, b1 = w1 / den, b2 = w2 / den;
                float z = (b0*F_[9] + b1*F_[10]) + b2*F_[11];
                if (z < zmin) {
                    zmin = z; idxsel = base + j;
                    b0s = b0; b1s = b1; b2s = b2;
                    covered = true;
                }
            }
        }
    }

    // interpolated features of selected face
    float u = 0.0f, v = 0.0f, m = 0.0f;
    if (covered) {
        const Face* Fs = fb + idxsel;
        u = (b0s*Fs->u0x + b1s*Fs->u1x) + b2s*Fs->u2x;
        v = (b0s*Fs->u0y + b1s*Fs->u1y) + b2s*Fs->u2y;
        m = (b0s + b1s) + b2s;
    }

    // fragment shader: g = remainder(uv,1)*2-1, gy negated; nearest grid_sample
    float gu = (u - floorf(u)) * 2.0f - 1.0f;
    float gv = (v - floorf(v)) * 2.0f - 1.0f;
    gv = -gv;
    float ix = ((gu + 1.0f) * (float)TW - 1.0f) * 0.5f;
    float iy = ((gv + 1.0f) * (float)TH - 1.0f) * 0.5f;
    float ixr = rintf(ix);   // round-half-even == jnp.round
    float iyr = rintf(iy);
    int ixn = (int)ixr, iyn = (int)iyr;
    bool tvalid = (ixn >= 0) && (ixn < TW) && (iyn >= 0) && (iyn < TH);
    int ixc = min(max(ixn, 0), TW-1);
    int iyc = min(max(iyn, 0), TH-1);
    float vmul = tvalid ? 1.0f : 0.0f;
    const float* tb = tex + (size_t)b * 3 * TH * TW;
    float tr = tb[(0*TH + iyc)*TW + ixc] * vmul;
    float tg = tb[(1*TH + iyc)*TW + ixc] * vmul;
    float tb2= tb[(2*TH + iyc)*TW + ixc] * vmul;

    float o0 = fminf(fmaxf(tr  * m, 0.0f), 1.0f);
    float o1 = fminf(fmaxf(tg  * m, 0.0f), 1.0f);
    float o2 = fminf(fmaxf(tb2 * m, 0.0f), 1.0f);

    float pr = 0.0f;
    if (hasfront) {
        float sxv = maxd / 0.02f;
        if (sxv >= 0.0f) pr = 1.0f / (1.0f + expf(-sxv));
        else { float e = expf(sxv); pr = e / (1.0f + e); }
    }

    float* outp = imrender + (size_t)pix * 3;
    outp[0] = o0; outp[1] = o1; outp[2] = o2;
    improb[pix] = pr;
}

extern "C" void kernel_launch(void* const* d_in, const int* in_sizes, int n_in,
                              void* d_out, int out_size, void* d_ws, size_t ws_size,
                              hipStream_t stream) {
    const float* points = (const float*)d_in[0];
    const int*   faces  = (const int*)  d_in[1];
    const float* rot    = (const float*)d_in[2];
    const float* cpos   = (const float*)d_in[3];
    const float* proj   = (const float*)d_in[4];
    const float* uvp    = (const float*)d_in[5];
    const float* tex    = (const float*)d_in[6];
    const int*   ft     = (const int*)  d_in[7];

    float* out        = (float*)d_out;
    float* imrender   = out;
    float* improb     = out + NB*IH*IW*3;
    float* normal_out = out + NB*IH*IW*3 + NB*IH*IW;
    Face*  fdata      = (Face*)d_ws;   // needs 2000*80 = 160 KB

    prep_kernel<<<(NB*NF + 255)/256, 256, 0, stream>>>(
        points, faces, rot, cpos, proj, uvp, ft, normal_out, fdata);
    raster_kernel<<<(NB*IH*IW)/BLK, BLK, 0, stream>>>(
        fdata, tex, imrender, improb);
}

// Round 2
// 57.726 us; speedup vs baseline: 4.5467x; 4.5467x over previous
//
#include <hip/hip_runtime.h>
#include <math.h>

#define NB 2
#define NP 1200
#define NF 1000
#define IH 128
#define IW 128
#define TH 512
#define TW 512

#define NGRP 8
#define FPG  125          // faces per group (NF / NGRP)
#define PIXB 64           // pixels per block
#define BLK  (NGRP * PIXB)

// 64-byte per-face record for the hot loop: c[9], z[3], front, pad x3
struct __align__(16) FaceC {
    float c[9];
    float z[3];
    float front;
    float pad0, pad1, pad2;
};

__global__ void prep_kernel(const float* __restrict__ points,
                            const int*  __restrict__ faces,
                            const float* __restrict__ rot,
                            const float* __restrict__ cpos,
                            const float* __restrict__ proj,
                            const int*  __restrict__ ft,   // unused here, kept for symmetry
                            float* __restrict__ normal_out,
                            FaceC* __restrict__ fdata)
{
#pragma clang fp contract(off)
    int t = blockIdx.x * blockDim.x + threadIdx.x;
    if (t >= NB * NF) return;
    int b = t / NF;
    int f = t - b * NF;
    const float* R = rot + b * 9;
    float ccx = cpos[b*3+0], ccy = cpos[b*3+1], ccz = cpos[b*3+2];
    float pr0 = proj[0], pr1 = proj[1], pr2 = proj[2];

    float q[3][3];
    float sx[3], sy[3];
    for (int k = 0; k < 3; ++k) {
        int vi = faces[f*3 + k];
        const float* P = points + (b*NP + vi) * 3;
        float vx = P[0] - ccx, vy = P[1] - ccy, vz = P[2] - ccz;
        float q0 = (vx*R[0] + vy*R[1]) + vz*R[2];
        float q1 = (vx*R[3] + vy*R[4]) + vz*R[5];
        float q2 = (vx*R[6] + vy*R[7]) + vz*R[8];
        q[k][0] = q0; q[k][1] = q1; q[k][2] = q2;
        sx[k] = (q0*pr0) / (q2*pr2);   // IEEE divide, reference order
        sy[k] = (q1*pr1) / (q2*pr2);
    }

    FaceC fd;
    float x0 = sx[0], y0 = sy[0];
    float x1 = sx[1], y1 = sy[1];
    float x2 = sx[2], y2 = sy[2];
    fd.c[0] = y1 - y2;  fd.c[1] = x2 - x1;  fd.c[2] = x1*y2 - x2*y1;
    fd.c[3] = y2 - y0;  fd.c[4] = x0 - x2;  fd.c[5] = x2*y0 - x0*y2;
    fd.c[6] = y0 - y1;  fd.c[7] = x1 - x0;  fd.c[8] = x0*y1 - x1*y0;
    fd.z[0] = q[0][2]; fd.z[1] = q[1][2]; fd.z[2] = q[2][2];

    float e1x = q[1][0]-q[0][0], e1y = q[1][1]-q[0][1], e1z = q[1][2]-q[0][2];
    float e2x = q[2][0]-q[0][0], e2y = q[2][1]-q[0][1], e2z = q[2][2]-q[0][2];
    float nx = e1y*e2z - e1z*e2y;
    float ny = e1z*e2x - e1x*e2z;
    float nz = e1x*e2y - e1y*e2x;
    fd.front = (nz > 0.0f) ? 1.0f : 0.0f;
    float nlen = sqrtf(((nx*nx + ny*ny) + nz*nz) + 1e-8f);
    float nd = nlen + 1e-15f;
    normal_out[t*3+0] = nx / nd;
    normal_out[t*3+1] = ny / nd;
    normal_out[t*3+2] = nz / nd;
    fd.pad0 = fd.pad1 = fd.pad2 = 0.0f;
    fdata[t] = fd;
}

// LDS: face cache (1000 * 64B = 64000B), reused after the loop for partials
// (512 records * 9 floats * 4B = 18432B).
__global__ __launch_bounds__(BLK) void raster_kernel(
        const FaceC* __restrict__ fdata,
        const float* __restrict__ tex,
        const float* __restrict__ uvp,
        const int*  __restrict__ ft,
        float* __restrict__ imrender,
        float* __restrict__ improb)
{
#pragma clang fp contract(off)
    __shared__ __align__(16) float lds[NF * 16];   // 64000 B

    int t = threadIdx.x;
    int g = t >> 6;           // face-group / wave id (0..7)
    int l = t & 63;           // pixel lane within block
    int pixbase = blockIdx.x * PIXB;
    int pix = pixbase + l;
    int b = pix >> 14;        // / (IH*IW)
    int p = pix & (IH*IW - 1);
    int py_i = p >> 7;        // / IW
    int px_i = p & (IW - 1);
    float px = (px_i + 0.5f) / (float)IW * 2.0f - 1.0f;
    float py = 1.0f - (py_i + 0.5f) / (float)IH * 2.0f;

    // --- stage all NF faces of this batch into LDS (coalesced float4) ---
    {
        const float4* src = (const float4*)(fdata + b * NF);
        float4* dst = (float4*)lds;
        for (int i = t; i < NF * 4; i += BLK) dst[i] = src[i];
    }
    __syncthreads();

    float zmin = INFINITY;
    int idxsel = -1;
    float b0s = 0.0f, b1s = 0.0f, b2s = 0.0f;
    bool covered = false;
    float maxd = -INFINITY;
    bool hasfront = false;

    int base = g * FPG;
#pragma unroll 5
    for (int j = 0; j < FPG; ++j) {
        const float* F_ = lds + (base + j) * 16;
        float w0 = (F_[0]*px + F_[1]*py) + F_[2];
        float w1 = (F_[3]*px + F_[4]*py) + F_[5];
        float w2 = (F_[6]*px + F_[7]*py) + F_[8];
        float den = (w0 + w1) + w2;
        den = den + ((den >= 0.0f) ? 1e-8f : -1e-8f);
        bool sp = den > 0.0f;
        float mn = fminf(fminf(w0, w1), w2);
        float mx = fmaxf(fmaxf(w0, w1), w2);
        float wsel = sp ? mn : mx;
        // fast rcp: only feeds max->sigmoid, 1-ulp error is far below threshold
        float dmin = wsel * __builtin_amdgcn_rcpf(den);
        float fr = F_[12];
        if (fr > 0.0f) { maxd = fmaxf(maxd, dmin); hasfront = true; }
        bool inside = sp ? (w0 >= 0.0f && w1 >= 0.0f && w2 >= 0.0f)
                         : (w0 <= 0.0f && w1 <= 0.0f && w2 <= 0.0f);
        if (inside && fr > 0.0f) {
            float b0 = w0 / den, b1 = w1 / den, b2 = w2 / den;   // IEEE, reference path
            float z = (b0*F_[9] + b1*F_[10]) + b2*F_[11];
            if (z < zmin) {
                zmin = z; idxsel = base + j;
                b0s = b0; b1s = b1; b2s = b2;
                covered = true;
            }
        }
    }

    // --- write partials (alias face LDS after barrier) ---
    __syncthreads();
    {
        float* rec = lds + t * 9;
        rec[0] = zmin;
        rec[1] = __int_as_float(idxsel);
        rec[2] = b0s; rec[3] = b1s; rec[4] = b2s;
        rec[5] = maxd;
        rec[6] = __int_as_float((covered ? 1 : 0) | (hasfront ? 2 : 0));
    }
    __syncthreads();

    if (t < PIXB) {
        // reduce the 8 group partials for pixel lane l = t
        float zb = INFINITY, rb0 = 0.0f, rb1 = 0.0f, rb2 = 0.0f;
        int fsel = -1;
        bool cov = false, hf = false;
        float md = -INFINITY;
        for (int gg = 0; gg < NGRP; ++gg) {
            const float* rec = lds + (gg * PIXB + t) * 9;
            int flags = __float_as_int(rec[6]);
            float zg = rec[0];
            if ((flags & 1) && zg < zb) {
                zb = zg; fsel = __float_as_int(rec[1]);
                rb0 = rec[2]; rb1 = rec[3]; rb2 = rec[4];
                cov = true;
            }
            md = fmaxf(md, rec[5]);
            hf = hf || (flags & 2);
        }

        // interpolated features of selected face (uv gathered from global)
        float u = 0.0f, v = 0.0f, m = 0.0f;
        if (cov) {
            int j0 = ft[fsel*3+0], j1 = ft[fsel*3+1], j2 = ft[fsel*3+2];
            const float* ub = uvp + (size_t)b * NP * 2;
            float u0x = ub[j0*2+0], u0y = ub[j0*2+1];
            float u1x = ub[j1*2+0], u1y = ub[j1*2+1];
            float u2x = ub[j2*2+0], u2y = ub[j2*2+1];
            u = (rb0*u0x + rb1*u1x) + rb2*u2x;
            v = (rb0*u0y + rb1*u1y) + rb2*u2y;
            m = (rb0 + rb1) + rb2;
        }

        float gu = (u - floorf(u)) * 2.0f - 1.0f;
        float gv = (v - floorf(v)) * 2.0f - 1.0f;
        gv = -gv;
        float ix = ((gu + 1.0f) * (float)TW - 1.0f) * 0.5f;
        float iy = ((gv + 1.0f) * (float)TH - 1.0f) * 0.5f;
        float ixr = rintf(ix);
        float iyr = rintf(iy);
        int ixn = (int)ixr, iyn = (int)iyr;
        bool tvalid = (ixn >= 0) && (ixn < TW) && (iyn >= 0) && (iyn < TH);
        int ixc = min(max(ixn, 0), TW-1);
        int iyc = min(max(iyn, 0), TH-1);
        float vmul = tvalid ? 1.0f : 0.0f;
        const float* tb = tex + (size_t)b * 3 * TH * TW;
        float tr  = tb[(0*TH + iyc)*TW + ixc] * vmul;
        float tg  = tb[(1*TH + iyc)*TW + ixc] * vmul;
        float tb2 = tb[(2*TH + iyc)*TW + ixc] * vmul;

        float o0 = fminf(fmaxf(tr  * m, 0.0f), 1.0f);
        float o1 = fminf(fmaxf(tg  * m, 0.0f), 1.0f);
        float o2 = fminf(fmaxf(tb2 * m, 0.0f), 1.0f);

        float pr = 0.0f;
        if (hf) {
            float sxv = md / 0.02f;
            if (sxv >= 0.0f) pr = 1.0f / (1.0f + expf(-sxv));
            else { float e = expf(sxv); pr = e / (1.0f + e); }
        }

        int opix = pixbase + t;
        float* outp = imrender + (size_t)opix * 3;
        outp[0] = o0; outp[1] = o1; outp[2] = o2;
        improb[opix] = pr;
    }
}

extern "C" void kernel_launch(void* const* d_in, const int* in_sizes, int n_in,
                              void* d_out, int out_size, void* d_ws, size_t ws_size,
                              hipStream_t stream) {
    const float* points = (const float*)d_in[0];
    const int*   faces  = (const int*)  d_in[1];
    const float* rot    = (const float*)d_in[2];
    const float* cpos   = (const float*)d_in[3];
    const float* proj   = (const float*)d_in[4];
    const float* uvp    = (const float*)d_in[5];
    const float* tex    = (const float*)d_in[6];
    const int*   ft     = (const int*)  d_in[7];

    float* out        = (float*)d_out;
    float* imrender   = out;
    float* improb     = out + NB*IH*IW*3;
    float* normal_out = out + NB*IH*IW*3 + NB*IH*IW;
    FaceC* fdata      = (FaceC*)d_ws;   // 2000 * 64 = 128 KB

    prep_kernel<<<(NB*NF + 255)/256, 256, 0, stream>>>(
        points, faces, rot, cpos, proj, ft, normal_out, fdata);
    raster_kernel<<<(NB*IH*IW)/PIXB, BLK, 0, stream>>>(
        fdata, tex, uvp, ft, imrender, improb);
}